// Round 1
// baseline (779.695 us; speedup 1.0000x reference)
//
#include <hip/hip_runtime.h>
#include <stdint.h>
#include <math.h>

// LightweightTransformerLayer fused implementation for gfx950.
// B=8, C=256, N=64, P=256; 512 sequences of [256 tokens x 256 ch].
//
// prep: fp32->bf16 weights into ws (W_q scaled by SCALE*log2e).
// k1  : per-sequence WG: LN1 -> h in registers (A-frags) -> per-head QKV gen
//       (W staged in LDS) -> flash attn (S^T = K Q^T trick) -> proj + bias +
//       residual -> x2 fp32 to d_out, LN2 -> h2 bf16 to ws.
// k2  : per-64-token WG: h2 -> MLP1 + exact GELU -> m1 (LDS) -> MLP2 -> RMW d_out.

#define DEV static __device__ __forceinline__

typedef __bf16 bf16x8 __attribute__((ext_vector_type(8)));
typedef float  f32x4  __attribute__((ext_vector_type(4)));

union B8 { bf16x8 v; uint4 q; uint32_t u[4]; uint16_t h[8]; };

DEV uint16_t f2bf(float f) {
  uint32_t u = __float_as_uint(f);
  return (uint16_t)((u + 0x7FFFu + ((u >> 16) & 1u)) >> 16);  // RNE
}
DEV float bf2f(uint16_t h) { return __uint_as_float(((uint32_t)h) << 16); }
DEV uint32_t pk2(float a, float b) { return (uint32_t)f2bf(a) | ((uint32_t)f2bf(b) << 16); }

DEV f32x4 mfma16(const B8& a, const B8& b, f32x4 c) {
  return __builtin_amdgcn_mfma_f32_16x16x32_bf16(a.v, b.v, c, 0, 0, 0);
}

DEV uint32_t shfl_u(uint32_t v, int src) { return (uint32_t)__shfl((int)v, src, 64); }

DEV B8 mk(const uint32_t* w) {
  B8 x; x.u[0] = w[0]; x.u[1] = w[1]; x.u[2] = w[2]; x.u[3] = w[3]; return x;
}

// Transpose C-frags (4 row-tiles of 16, regs packed as bf16 pairs pk0=(r0,r1),
// pk1=(r2,r3)) into an A/B-frag: lane 16g+r receives rows 32*kd+8g..+7 at col r.
// Verified mapping: C/D col=lane&15, row=(lane>>4)*4+i ; A/B idx=lane&15, k-octet=(lane>>4)*8.
DEV void xpose(const uint32_t* pk0, const uint32_t* pk1, int kd, int g, int r, uint32_t* out) {
  const int sA = 32 * (g & 1) + r;
  const int sB = sA + 16;
  const int tA = 2 * kd, tB = 2 * kd + 1;
  uint32_t a0 = shfl_u(pk0[tA], sA), b0 = shfl_u(pk0[tB], sA);
  uint32_t a1 = shfl_u(pk1[tA], sA), b1 = shfl_u(pk1[tB], sA);
  uint32_t a2 = shfl_u(pk0[tA], sB), b2 = shfl_u(pk0[tB], sB);
  uint32_t a3 = shfl_u(pk1[tA], sB), b3 = shfl_u(pk1[tB], sB);
  const bool hi = g >= 2;
  out[0] = hi ? b0 : a0;
  out[1] = hi ? b1 : a1;
  out[2] = hi ? b2 : a2;
  out[3] = hi ? b3 : a3;
}

// ---------------------------------------------------------------------------
// prep: convert weights to bf16 into ws. Layout (bf16 elems):
//   [0)        Wqkv  [768][256]   (rows 0..255 = W_q, scaled by SCALE*log2e)
//   [196608)   Wproj [256][256]
//   [262144)   Wmlp1 [512][256]
//   [393216)   Wmlp2 [256][512]
//   [524288)   h2    [512][256][256]
__global__ void transformer_prep(const float* __restrict__ wqkv,
                                 const float* __restrict__ wproj,
                                 const float* __restrict__ w1,
                                 const float* __restrict__ w2,
                                 uint16_t* __restrict__ wbf) {
  int e = blockIdx.x * 256 + threadIdx.x;  // grid 2048*256 = 524288 exactly
  float v;
  if (e < 196608)      v = wqkv[e] * (e < 65536 ? 0.18033688011112042f : 1.0f);
  else if (e < 262144) v = wproj[e - 196608];
  else if (e < 393216) v = w1[e - 262144];
  else                 v = w2[e - 393216];
  wbf[e] = f2bf(v);
}

// ---------------------------------------------------------------------------
// k1 LDS map (163840 B total):
//  phase1: chunk buffer f32 [64][264]               @0      (67584 B)
//  phase2: K   bf16 [q 256][d 64]  (pitch 128B)     @0      (32768)
//          V^T bf16 [d 64][q 256]  (pitch 512B)     @32768  (32768)
//          Wq/Wk/Wv head slices [64][256] bf16      @65536  (3*32768)
//  phase3: x2 bf16 [p 256][c 256] (pitch 512B)      @0      (131072)
//          Wproj quarter [64][256] bf16 / stats     @131072 (32768)
// All row-major tiles swizzled: byte ^= (row&7)<<4.
__global__ __launch_bounds__(512, 2) void transformer_k1(
    const float* __restrict__ x,
    const float* __restrict__ bproj,
    const float* __restrict__ ln1g, const float* __restrict__ ln1b,
    const float* __restrict__ ln2g, const float* __restrict__ ln2b,
    const uint16_t* __restrict__ wbf,
    uint16_t* __restrict__ h2,
    float* __restrict__ out) {
  __shared__ __attribute__((aligned(16))) uint8_t lds[163840];
  const int tid = threadIdx.x;
  const int lane = tid & 63;
  const int wv = tid >> 6;       // wave 0..7, owns token rows 32*wv..+32
  const int r = lane & 15;
  const int g = lane >> 4;
  const int s = blockIdx.x;      // sequence = b*64 + n
  const int bb = s >> 6, nn = s & 63;
  const float* xs = x + (size_t)bb * 4194304 + (size_t)nn * 256;  // (c,p) at c*16384+p
  float* outp = out + (size_t)bb * 4194304 + (size_t)nn * 256;
  const f32x4 fz = {0.f, 0.f, 0.f, 0.f};

  // ================= Phase 1: x -> LN1 -> h as register A-frags =============
  // hfrag[rt][kt]: h[row = 32wv+16rt+(lane&15)][c = 32kt+8g .. +8] as bf16x8.
  uint32_t hfrag[2][8][4];
  float s1[2] = {0.f, 0.f}, s2[2] = {0.f, 0.f};
#pragma unroll
  for (int ch = 0; ch < 4; ++ch) {
#pragma unroll
    for (int i = 0; i < 8; ++i) {              // stage 64 c-rows x 256 p (f32)
      int f = i * 512 + tid;
      int c = f >> 6;
      int p4 = (f & 63) << 2;
      f32x4 v = *(const f32x4*)(xs + (size_t)(ch * 64 + c) * 16384 + p4);
      *(f32x4*)(lds + (c * 264 + p4) * 4) = v;  // pitch 264 f32 (bank-friendly)
    }
    __syncthreads();
#pragma unroll
    for (int rt = 0; rt < 2; ++rt) {
      int p = 32 * wv + 16 * rt + r;
#pragma unroll
      for (int ktl = 0; ktl < 2; ++ktl) {
        int cl0 = 32 * ktl + 8 * g;
        float v[8];
#pragma unroll
        for (int j = 0; j < 8; ++j) {
          v[j] = *(const float*)(lds + ((cl0 + j) * 264 + p) * 4);
          s1[rt] += v[j];
          s2[rt] += v[j] * v[j];
        }
#pragma unroll
        for (int w = 0; w < 4; ++w) hfrag[rt][2 * ch + ktl][w] = pk2(v[2 * w], v[2 * w + 1]);
      }
    }
    __syncthreads();
  }
  float mu[2], rs[2];
#pragma unroll
  for (int rt = 0; rt < 2; ++rt) {  // lanes r,r+16,r+32,r+48 share a row
    float a = s1[rt]; a += __shfl_xor(a, 16, 64); a += __shfl_xor(a, 32, 64);
    float b = s2[rt]; b += __shfl_xor(b, 16, 64); b += __shfl_xor(b, 32, 64);
    mu[rt] = a * (1.0f / 256.0f);
    float var = b * (1.0f / 256.0f) - mu[rt] * mu[rt];
    rs[rt] = rsqrtf(var + 1e-5f);
  }
#pragma unroll
  for (int kt = 0; kt < 8; ++kt) {  // normalize in place
    int c0 = 32 * kt + 8 * g;
    f32x4 gA = *(const f32x4*)(ln1g + c0), gB = *(const f32x4*)(ln1g + c0 + 4);
    f32x4 bA = *(const f32x4*)(ln1b + c0), bB = *(const f32x4*)(ln1b + c0 + 4);
#pragma unroll
    for (int rt = 0; rt < 2; ++rt) {
#pragma unroll
      for (int w = 0; w < 4; ++w) {
        uint32_t pw = hfrag[rt][kt][w];
        float lo = bf2f((uint16_t)(pw & 0xFFFFu));
        float hi = bf2f((uint16_t)(pw >> 16));
        float glo = (w < 2) ? gA[2 * w] : gB[2 * w - 4];
        float ghi = (w < 2) ? gA[2 * w + 1] : gB[2 * w - 3];
        float blo = (w < 2) ? bA[2 * w] : bB[2 * w - 4];
        float bhi = (w < 2) ? bA[2 * w + 1] : bB[2 * w - 3];
        lo = (lo - mu[rt]) * rs[rt] * glo + blo;
        hi = (hi - mu[rt]) * rs[rt] * ghi + bhi;
        hfrag[rt][kt][w] = pk2(lo, hi);
      }
    }
  }
  __syncthreads();

  // ================= Phase 2: attention heads ===============================
  // oa[pt][kt] accumulates attn output o[p][c] as proj A-frags (c = 64*hd + d).
  uint32_t oa[2][8][4];
#pragma unroll
  for (int hd = 0; hd < 4; ++hd) {
    // stage this head's Wq/Wk/Wv rows [hd*64..+64) of Wqkv[768][256]
#pragma unroll
    for (int m = 0; m < 3; ++m) {
      const uint16_t* src = wbf + (m * 256 + hd * 64) * 256;
#pragma unroll
      for (int i = 0; i < 4; ++i) {
        int f = i * 512 + tid;
        int row = f >> 5, c16 = f & 31;
        uint4 v = *(const uint4*)(src + row * 256 + c16 * 8);
        *(uint4*)(lds + ((65536 + m * 32768 + row * 512 + c16 * 16) ^ ((row & 7) << 4))) = v;
      }
    }
    __syncthreads();  // W staged (also: previous flash readers done before KV writes)

    // ---- K (m=0) and V^T (m=1) generation; wave computes its own 32 rows
#pragma unroll
    for (int m = 0; m < 2; ++m) {
      const int wb_base = 65536 + (m + 1) * 32768;
      f32x4 acc[2][4];
#pragma unroll
      for (int rt = 0; rt < 2; ++rt)
#pragma unroll
        for (int ct = 0; ct < 4; ++ct) acc[rt][ct] = fz;
#pragma unroll
      for (int kt = 0; kt < 8; ++kt) {
#pragma unroll
        for (int ct = 0; ct < 4; ++ct) {
          B8 wfr;
          wfr.q = *(const uint4*)(lds + ((wb_base + (16 * ct + r) * 512 + (32 * kt + 8 * g) * 2) ^ ((r & 7) << 4)));
#pragma unroll
          for (int rt = 0; rt < 2; ++rt) {
            B8 a = mk(hfrag[rt][kt]);
            acc[rt][ct] = mfma16(a, wfr, acc[rt][ct]);
          }
        }
      }
#pragma unroll
      for (int rt = 0; rt < 2; ++rt) {
#pragma unroll
        for (int ct = 0; ct < 4; ++ct) {
          int d = 16 * ct + r;
          int q0 = 32 * wv + 16 * rt + 4 * g;
          if (m == 0) {  // K[q][d], pitch 128B
#pragma unroll
            for (int i = 0; i < 4; ++i) {
              int qq = q0 + i;
              *(uint16_t*)(lds + ((qq * 128 + d * 2) ^ ((qq & 7) << 4))) = f2bf(acc[rt][ct][i]);
            }
          } else {       // V^T[d][q], pitch 512B, 4 consecutive q packed
            uint2 pv;
            pv.x = pk2(acc[rt][ct][0], acc[rt][ct][1]);
            pv.y = pk2(acc[rt][ct][2], acc[rt][ct][3]);
            *(uint2*)(lds + ((32768 + d * 512 + q0 * 2) ^ ((d & 7) << 4))) = pv;
          }
        }
      }
    }
    __syncthreads();  // K/V ready

    // ---- flash attention; pt-sequential (2 x 16 query rows) to cap VGPRs
#pragma unroll
    for (int pt = 0; pt < 2; ++pt) {
      // Q^T[d 64][p 16] = (SCALE*log2e*Wq) x h
      f32x4 qT[4];
#pragma unroll
      for (int mt = 0; mt < 4; ++mt) qT[mt] = fz;
#pragma unroll
      for (int kt = 0; kt < 8; ++kt) {
        B8 hb = mk(hfrag[pt][kt]);
#pragma unroll
        for (int mt = 0; mt < 4; ++mt) {
          B8 wa;
          wa.q = *(const uint4*)(lds + ((65536 + (16 * mt + r) * 512 + (32 * kt + 8 * g) * 2) ^ ((r & 7) << 4)));
          qT[mt] = mfma16(wa, hb, qT[mt]);
        }
      }
      uint32_t pq0[4], pq1[4];
#pragma unroll
      for (int mt = 0; mt < 4; ++mt) {
        pq0[mt] = pk2(qT[mt][0], qT[mt][1]);
        pq1[mt] = pk2(qT[mt][2], qT[mt][3]);
      }
      uint32_t qb[2][4];
#pragma unroll
      for (int kd = 0; kd < 2; ++kd) xpose(pq0, pq1, kd, g, r, qb[kd]);

      float m_ = -1e30f, l_ = 0.f;
      f32x4 oT[4];
#pragma unroll
      for (int dt = 0; dt < 4; ++dt) oT[dt] = fz;

#pragma unroll 1
      for (int chk = 0; chk < 4; ++chk) {  // 64 keys per step, kept rolled
        f32x4 sT[4];
#pragma unroll
        for (int qt = 0; qt < 4; ++qt) sT[qt] = fz;
#pragma unroll
        for (int kd = 0; kd < 2; ++kd) {
          B8 qf = mk(qb[kd]);
#pragma unroll
          for (int qt = 0; qt < 4; ++qt) {
            int qq = chk * 64 + 16 * qt + r;
            B8 ka;
            ka.q = *(const uint4*)(lds + ((qq * 128 + (32 * kd + 8 * g) * 2) ^ ((qq & 7) << 4)));
            sT[qt] = mfma16(ka, qf, sT[qt]);  // S^T[q][p], log2-domain
          }
        }
        // online softmax over q (16 in-lane values + g-butterfly)
        float tmax = sT[0][0];
#pragma unroll
        for (int qt = 0; qt < 4; ++qt)
#pragma unroll
          for (int i = 0; i < 4; ++i) tmax = fmaxf(tmax, sT[qt][i]);
        tmax = fmaxf(tmax, __shfl_xor(tmax, 16, 64));
        tmax = fmaxf(tmax, __shfl_xor(tmax, 32, 64));
        float mn = fmaxf(m_, tmax);
        float fcor = exp2f(m_ - mn);
        float ts = 0.f;
#pragma unroll
        for (int qt = 0; qt < 4; ++qt)
#pragma unroll
          for (int i = 0; i < 4; ++i) {
            float e = exp2f(sT[qt][i] - mn);
            sT[qt][i] = e;
            ts += e;
          }
        ts += __shfl_xor(ts, 16, 64);
        ts += __shfl_xor(ts, 32, 64);
        l_ = l_ * fcor + ts;
        m_ = mn;
#pragma unroll
        for (int dt = 0; dt < 4; ++dt)
#pragma unroll
          for (int i = 0; i < 4; ++i) oT[dt][i] *= fcor;
        // P^T C-frags -> PV B-frags (in-register shuffle transpose)
        uint32_t pp0[4], pp1[4];
#pragma unroll
        for (int qt = 0; qt < 4; ++qt) {
          pp0[qt] = pk2(sT[qt][0], sT[qt][1]);
          pp1[qt] = pk2(sT[qt][2], sT[qt][3]);
        }
#pragma unroll
        for (int qk = 0; qk < 2; ++qk) {
          uint32_t pb[4];
          xpose(pp0, pp1, qk, g, r, pb);
          B8 pf = mk(pb);
#pragma unroll
          for (int dt = 0; dt < 4; ++dt) {
            B8 va;
            va.q = *(const uint4*)(lds + ((32768 + (16 * dt + r) * 512 + (chk * 64 + 32 * qk + 8 * g) * 2) ^ ((r & 7) << 4)));
            oT[dt] = mfma16(va, pf, oT[dt]);  // O^T[d][p]
          }
        }
      }
      float inv = 1.0f / l_;
      uint32_t po0[4], po1[4];
#pragma unroll
      for (int dt = 0; dt < 4; ++dt) {
        po0[dt] = pk2(oT[dt][0] * inv, oT[dt][1] * inv);
        po1[dt] = pk2(oT[dt][2] * inv, oT[dt][3] * inv);
      }
#pragma unroll
      for (int kd = 0; kd < 2; ++kd) xpose(po0, po1, kd, g, r, oa[pt][2 * hd + kd]);
    }
    __syncthreads();  // flash done before next head restages W
  }

  // ================= Phase 3: proj + bias + residual -> x2 (d_out) + LN2 ====
  const uint16_t* wp = wbf + 196608;
  float s1r[2][4], s2r[2][4];
#pragma unroll
  for (int rt = 0; rt < 2; ++rt)
#pragma unroll
    for (int i = 0; i < 4; ++i) { s1r[rt][i] = 0.f; s2r[rt][i] = 0.f; }
#pragma unroll 1
  for (int q3 = 0; q3 < 4; ++q3) {  // 64 output channels per step
#pragma unroll
    for (int i = 0; i < 4; ++i) {   // stage Wproj quarter @131072
      int f = i * 512 + tid;
      int row = f >> 5, c16 = f & 31;
      uint4 v = *(const uint4*)(wp + (q3 * 64 + row) * 256 + c16 * 8);
      *(uint4*)(lds + ((131072 + row * 512 + c16 * 16) ^ ((row & 7) << 4))) = v;
    }
    __syncthreads();
    f32x4 acc[2][4];
#pragma unroll
    for (int rt = 0; rt < 2; ++rt)
#pragma unroll
      for (int ct = 0; ct < 4; ++ct) acc[rt][ct] = fz;
#pragma unroll
    for (int kt = 0; kt < 8; ++kt) {
#pragma unroll
      for (int ct = 0; ct < 4; ++ct) {
        B8 wfr;
        wfr.q = *(const uint4*)(lds + ((131072 + (16 * ct + r) * 512 + (32 * kt + 8 * g) * 2) ^ ((r & 7) << 4)));
#pragma unroll
        for (int rt = 0; rt < 2; ++rt) {
          B8 a = mk(oa[rt][kt]);
          acc[rt][ct] = mfma16(a, wfr, acc[rt][ct]);
        }
      }
    }
#pragma unroll
    for (int rt = 0; rt < 2; ++rt) {
#pragma unroll
      for (int ct = 0; ct < 4; ++ct) {
        int c = q3 * 64 + 16 * ct + r;
        float bias = bproj[c];
        int p0 = 32 * wv + 16 * rt + 4 * g;
        f32x4 res = *(const f32x4*)(xs + (size_t)c * 16384 + p0);
        f32x4 x2v;
#pragma unroll
        for (int i = 0; i < 4; ++i) x2v[i] = acc[rt][ct][i] + bias + res[i];
        *(f32x4*)(outp + (size_t)c * 16384 + p0) = x2v;  // x2 fp32 -> d_out
#pragma unroll
        for (int i = 0; i < 4; ++i) {
          s1r[rt][i] += x2v[i];
          s2r[rt][i] += x2v[i] * x2v[i];
          int pp = p0 + i;
          *(uint16_t*)(lds + ((pp * 512 + c * 2) ^ ((pp & 7) << 4))) = f2bf(x2v[i]);  // x2 bf16
        }
      }
    }
    __syncthreads();
  }
  // LN2 stats: butterfly over the 16-lane col dimension
#pragma unroll
  for (int rt = 0; rt < 2; ++rt)
#pragma unroll
    for (int i = 0; i < 4; ++i) {
      float a = s1r[rt][i], b = s2r[rt][i];
#pragma unroll
      for (int off = 1; off < 16; off <<= 1) {
        a += __shfl_xor(a, off, 64);
        b += __shfl_xor(b, off, 64);
      }
      float m = a * (1.0f / 256.0f);
      float var = b * (1.0f / 256.0f) - m * m;
      s1r[rt][i] = m;
      s2r[rt][i] = rsqrtf(var + 1e-5f);
    }
  if (r == 0) {
#pragma unroll
    for (int rt = 0; rt < 2; ++rt)
#pragma unroll
      for (int i = 0; i < 4; ++i) {
        int pp = 32 * wv + 16 * rt + 4 * g + i;
        float2 st; st.x = s1r[rt][i]; st.y = s2r[rt][i];
        *(float2*)(lds + 131072 + pp * 8) = st;
      }
  }
  __syncthreads();
  // h2 = LN2(x2) -> ws (row-major [s][p][c] bf16)
  {
    int pp = tid >> 1;
    int chf = tid & 1;
    float2 st = *(const float2*)(lds + 131072 + pp * 8);
#pragma unroll
    for (int kk = 0; kk < 16; ++kk) {
      int c0 = chf * 128 + kk * 8;
      B8 xv;
      xv.q = *(const uint4*)(lds + ((pp * 512 + c0 * 2) ^ ((pp & 7) << 4)));
      f32x4 gA = *(const f32x4*)(ln2g + c0), gB = *(const f32x4*)(ln2g + c0 + 4);
      f32x4 bA = *(const f32x4*)(ln2b + c0), bB = *(const f32x4*)(ln2b + c0 + 4);
      B8 ov;
#pragma unroll
      for (int j = 0; j < 8; ++j) {
        float v = bf2f(xv.h[j]);
        float gg = (j < 4) ? gA[j & 3] : gB[j & 3];
        float bb2 = (j < 4) ? bA[j & 3] : bB[j & 3];
        v = (v - st.x) * st.y * gg + bb2;
        ov.h[j] = f2bf(v);
      }
      *(uint4*)(h2 + (size_t)s * 65536 + pp * 256 + c0) = ov.q;
    }
  }
}

// ---------------------------------------------------------------------------
// k2: MLP. WG = (sequence s, 64-token group tg). LDS: h2 tile 32KB + m1 64KB.
__global__ __launch_bounds__(512, 2) void transformer_k2(
    const uint16_t* __restrict__ h2,
    const uint16_t* __restrict__ w1,
    const uint16_t* __restrict__ w2,
    const float* __restrict__ bm1,
    const float* __restrict__ bm2,
    float* __restrict__ out) {
  __shared__ __attribute__((aligned(16))) uint8_t lds[98304];
  const int tid = threadIdx.x;
  const int lane = tid & 63;
  const int wv = tid >> 6;
  const int r = lane & 15, g = lane >> 4;
  const int bid = blockIdx.x;
  const int s = bid >> 2, tg = bid & 3;
  const int bb = s >> 6, nn = s & 63;
  const f32x4 fz = {0.f, 0.f, 0.f, 0.f};

#pragma unroll
  for (int i = 0; i < 4; ++i) {  // stage h2 [64][256] bf16, swizzled
    int f = i * 512 + tid;
    int row = f >> 5, c16 = f & 31;
    uint4 v = *(const uint4*)(h2 + (size_t)s * 65536 + (tg * 64 + row) * 256 + c16 * 8);
    *(uint4*)(lds + ((row * 512 + c16 * 16) ^ ((row & 7) << 4))) = v;
  }
  __syncthreads();

  // GEMM1: [64 tok][256] x W1^T[256][512]; wave owns 64 hidden cols
  f32x4 acc[4][4];
#pragma unroll
  for (int mt = 0; mt < 4; ++mt)
#pragma unroll
    for (int nt = 0; nt < 4; ++nt) acc[mt][nt] = fz;
#pragma unroll
  for (int kt = 0; kt < 8; ++kt) {
    B8 a[4];
#pragma unroll
    for (int mt = 0; mt < 4; ++mt)
      a[mt].q = *(const uint4*)(lds + (((16 * mt + r) * 512 + (32 * kt + 8 * g) * 2) ^ ((r & 7) << 4)));
#pragma unroll
    for (int nt = 0; nt < 4; ++nt) {
      B8 bfr;
      bfr.q = *(const uint4*)(w1 + ((64 * wv + 16 * nt + r) * 256 + 32 * kt + 8 * g));
#pragma unroll
      for (int mt = 0; mt < 4; ++mt) acc[mt][nt] = mfma16(a[mt], bfr, acc[mt][nt]);
    }
  }
#pragma unroll
  for (int nt = 0; nt < 4; ++nt) {
    int n = 64 * wv + 16 * nt + r;
    float bias = bm1[n];
#pragma unroll
    for (int mt = 0; mt < 4; ++mt) {
#pragma unroll
      for (int i = 0; i < 4; ++i) {
        float v = acc[mt][nt][i] + bias;
        v = 0.5f * v * (1.0f + erff(v * 0.70710678118654752440f));  // exact GELU
        int row = 16 * mt + 4 * g + i;
        *(uint16_t*)(lds + ((32768 + row * 1024 + n * 2) ^ ((row & 7) << 4))) = f2bf(v);
      }
    }
  }
  __syncthreads();

  // GEMM2: m1[64][512] x W2^T[512][256]; wave owns 32 output channels
  f32x4 acc2[4][2];
#pragma unroll
  for (int mt = 0; mt < 4; ++mt)
#pragma unroll
    for (int nt = 0; nt < 2; ++nt) acc2[mt][nt] = fz;
#pragma unroll
  for (int kt = 0; kt < 16; ++kt) {
    B8 a[4];
#pragma unroll
    for (int mt = 0; mt < 4; ++mt)
      a[mt].q = *(const uint4*)(lds + ((32768 + (16 * mt + r) * 1024 + (32 * kt + 8 * g) * 2) ^ ((r & 7) << 4)));
#pragma unroll
    for (int nt = 0; nt < 2; ++nt) {
      B8 bfr;
      bfr.q = *(const uint4*)(w2 + ((32 * wv + 16 * nt + r) * 512 + 32 * kt + 8 * g));
#pragma unroll
      for (int mt = 0; mt < 4; ++mt) acc2[mt][nt] = mfma16(a[mt], bfr, acc2[mt][nt]);
    }
  }
  float* outp = out + (size_t)bb * 4194304 + (size_t)nn * 256;
#pragma unroll
  for (int nt = 0; nt < 2; ++nt) {
    int c = 32 * wv + 16 * nt + r;
    float bias = bm2[c];
#pragma unroll
    for (int mt = 0; mt < 4; ++mt) {
      int p0 = tg * 64 + 16 * mt + 4 * g;
      f32x4 v = *(const f32x4*)(outp + (size_t)c * 16384 + p0);
#pragma unroll
      for (int i = 0; i < 4; ++i) v[i] += acc2[mt][nt][i] + bias;
      *(f32x4*)(outp + (size_t)c * 16384 + p0) = v;  // out = x2 + mlp
    }
  }
}

// ---------------------------------------------------------------------------
extern "C" void kernel_launch(void* const* d_in, const int* in_sizes, int n_in,
                              void* d_out, int out_size, void* d_ws, size_t ws_size,
                              hipStream_t stream) {
  (void)in_sizes; (void)n_in; (void)out_size; (void)ws_size;
  const float* x     = (const float*)d_in[0];
  const float* wqkv  = (const float*)d_in[1];
  const float* wproj = (const float*)d_in[2];
  const float* bproj = (const float*)d_in[3];
  const float* ln1g  = (const float*)d_in[4];
  const float* ln1b  = (const float*)d_in[5];
  const float* ln2g  = (const float*)d_in[6];
  const float* ln2b  = (const float*)d_in[7];
  const float* w1    = (const float*)d_in[8];
  const float* bm1   = (const float*)d_in[9];
  const float* w2    = (const float*)d_in[10];
  const float* bm2   = (const float*)d_in[11];
  uint16_t* wbf = (uint16_t*)d_ws;        // 524288 bf16 weights
  uint16_t* h2  = wbf + 524288;           // 33554432 bf16 h2 (needs ~65 MB ws)
  float* out = (float*)d_out;

  transformer_prep<<<2048, 256, 0, stream>>>(wqkv, wproj, w1, w2, wbf);
  transformer_k1<<<512, 512, 0, stream>>>(x, bproj, ln1g, ln1b, ln2g, ln2b, wbf, h2, out);
  transformer_k2<<<2048, 512, 0, stream>>>(h2, wbf + 262144, wbf + 393216, bm1, bm2, out);
}